// Round 8
// baseline (1253.150 us; speedup 1.0000x reference)
//
#include <hip/hip_runtime.h>

typedef _Float16 f16;
typedef _Float16 f16x2 __attribute__((ext_vector_type(2)));
typedef _Float16 f16x8 __attribute__((ext_vector_type(8)));
typedef float    f32x4 __attribute__((ext_vector_type(4)));

#define V  32000
#define E  128
#define H  128
#define B  32
#define T  128
#define G3 384   // 3H

// ---------- K0: fc_w (256,V) f32  ->  Bt16 (V,256) f16 (transposed, converted)
__global__ __launch_bounds__(256) void k0_convert_fcw(const float* __restrict__ fc_w,
                                                      f16* __restrict__ Bt16)
{
    int v  = blockIdx.x * 256 + threadIdx.x;   // coalesced across lanes
    int k0 = blockIdx.y * 64;
    for (int kk = 0; kk < 64; kk += 8) {
        f16x8 p;
        #pragma unroll
        for (int e = 0; e < 8; ++e)
            p[e] = (f16)fc_w[(size_t)(k0 + kk + e) * V + v];
        *(f16x8*)(Bt16 + (size_t)v * 256 + (k0 + kk)) = p;
    }
}

// ---------- K1: xg = embedding[x] @ W_ih + b    (B*T, 3H)
__global__ __launch_bounds__(384) void k1_embed_xg(const int* __restrict__ x,
                                                   const float* __restrict__ emb,
                                                   const float* __restrict__ W_ih,
                                                   const float* __restrict__ bias,
                                                   float* __restrict__ xg)
{
    int j = threadIdx.x;
    float w[E];
    #pragma unroll
    for (int k = 0; k < E; ++k) w[k] = W_ih[k * G3 + j];
    float bj = bias[j];

    __shared__ __align__(16) float erow[16][E];
    int row0 = blockIdx.x * 16;
    for (int i = j; i < 16 * E; i += G3) {
        int r = i >> 7, c = i & (E - 1);
        erow[r][c] = emb[(size_t)x[row0 + r] * E + c];
    }
    __syncthreads();
    for (int r = 0; r < 16; ++r) {
        float acc = bj;
        #pragma unroll
        for (int k = 0; k < E; k += 4) {
            f32x4 hv = *(const f32x4*)&erow[r][k];
            acc += hv[0]*w[k] + hv[1]*w[k+1] + hv[2]*w[k+2] + hv[3]*w[k+3];
        }
        xg[(size_t)(row0 + r) * G3 + j] = acc;
    }
}

// ---------- KSEQ: fused GRU scan + scores + causal softmax/context.
// One block per batch, 384 threads. W_hh col j in regs of thread j; threads
// j<128 also hold attn_w col j -> score dot reuses the SAME h[k] broadcast
// reads as the gates dot. hs lives entirely in LDS (64KB); context phase
// post-scan, waves parallel over t. Writes both halves of A16; no hs global.
__global__ __launch_bounds__(384) void kseq(const float* __restrict__ xg,
                                            const float* __restrict__ W_hh,
                                            const float* __restrict__ attn_w,
                                            const float* __restrict__ attn_b,
                                            const float* __restrict__ v_w,
                                            const float* __restrict__ v_b,
                                            f16* __restrict__ A16)
{
    int b    = blockIdx.x;
    int j    = threadIdx.x;
    int lane = j & 63;
    int wv   = j >> 6;               // wave 0..5

    float w[H];
    #pragma unroll
    for (int k = 0; k < H; ++k) w[k] = W_hh[k * G3 + j];

    float acol[H];
    float ab = 0.f, vwgt = 0.f;
    if (j < H) {
        #pragma unroll
        for (int k = 0; k < H; ++k) acol[k] = attn_w[k * H + j];
        ab = attn_b[j];
        vwgt = v_w[j];
    }
    float vb = v_b[0];

    __shared__ __align__(16) float h[H];
    __shared__ float g[G3];
    __shared__ float part[2];
    __shared__ float sc_lds[T];
    __shared__ __align__(16) float hs_lds[T][H];   // 64KB
    if (j < H) h[j] = 0.0f;
    __syncthreads();

    const float* xgb = xg + (size_t)b * T * G3;
    float xnext = xgb[j];
    for (int t = 0; t < T; ++t) {
        float s0 = xnext, s1 = 0.f, s2 = 0.f, s3 = 0.f;
        float sc0 = 0.f, sc1 = 0.f;
        if (t + 1 < T) xnext = xgb[(size_t)(t + 1) * G3 + j];
        #pragma unroll
        for (int k = 0; k < H; k += 16) {
            f32x4 h0 = *(const f32x4*)&h[k];
            f32x4 h1 = *(const f32x4*)&h[k + 4];
            f32x4 h2 = *(const f32x4*)&h[k + 8];
            f32x4 h3 = *(const f32x4*)&h[k + 12];
            s0 += h0[0]*w[k]    + h0[1]*w[k+1]  + h0[2]*w[k+2]  + h0[3]*w[k+3];
            s1 += h1[0]*w[k+4]  + h1[1]*w[k+5]  + h1[2]*w[k+6]  + h1[3]*w[k+7];
            s2 += h2[0]*w[k+8]  + h2[1]*w[k+9]  + h2[2]*w[k+10] + h2[3]*w[k+11];
            s3 += h3[0]*w[k+12] + h3[1]*w[k+13] + h3[2]*w[k+14] + h3[3]*w[k+15];
            if (j < H) {   // wave-uniform (waves 0,1)
                sc0 += h0[0]*acol[k]    + h0[1]*acol[k+1]  + h0[2]*acol[k+2]  + h0[3]*acol[k+3]
                     + h1[0]*acol[k+4]  + h1[1]*acol[k+5]  + h1[2]*acol[k+6]  + h1[3]*acol[k+7];
                sc1 += h2[0]*acol[k+8]  + h2[1]*acol[k+9]  + h2[2]*acol[k+10] + h2[3]*acol[k+11]
                     + h3[0]*acol[k+12] + h3[1]*acol[k+13] + h3[2]*acol[k+14] + h3[3]*acol[k+15];
            }
        }
        g[j] = (s0 + s1) + (s2 + s3);
        if (j < H && t > 0) {
            // score for h_{t-1}: u = tanh(sc + ab) * v_w[j], reduce over j
            float sc = sc0 + sc1 + ab;
            float ex = __expf(2.0f * sc);
            float u  = (1.0f - 2.0f / (ex + 1.0f)) * vwgt;
            #pragma unroll
            for (int o = 32; o > 0; o >>= 1) u += __shfl_xor(u, o);
            if (lane == 0) part[wv] = u;
        }
        __syncthreads();
        if (j < H) {
            float z  = 1.0f / (1.0f + __expf(-g[j]));
            float r  = 1.0f / (1.0f + __expf(-g[H + j]));
            float pn = g[2 * H + j] * r;
            float ex = __expf(2.0f * pn);
            float n  = 1.0f - 2.0f / (ex + 1.0f);      // tanh(pn)
            float hn = (1.0f - z) * n + z * h[j];
            h[j] = hn;
            hs_lds[t][j] = hn;
            A16[((size_t)b * T + t) * 256 + j] = (f16)hn;
        }
        if (j == 0 && t > 0) sc_lds[t - 1] = part[0] + part[1] + vb;
        __syncthreads();
    }

    // ---- context phase: waves parallel over t; lane owns cols 2*lane, 2*lane+1
    for (int t = wv; t < T; t += 6) {
        float sv0 = (lane < t)      ? sc_lds[lane]      : -3.0e38f;
        float sv1 = (lane + 64 < t) ? sc_lds[lane + 64] : -3.0e38f;
        float m = fmaxf(sv0, sv1);
        #pragma unroll
        for (int o = 32; o > 0; o >>= 1) m = fmaxf(m, __shfl_xor(m, o));
        float ee = ((lane < t)      ? __expf(sv0 - m) : 0.f)
                 + ((lane + 64 < t) ? __expf(sv1 - m) : 0.f);
        #pragma unroll
        for (int o = 32; o > 0; o >>= 1) ee += __shfl_xor(ee, o);
        float inv = (t > 0) ? 1.0f / ee : 0.0f;

        float c0 = 0.f, c1 = 0.f;
        for (int s = 0; s < t; ++s) {
            float ws = __expf(sc_lds[s] - m) * inv;
            float2 hv = *(const float2*)&hs_lds[s][lane * 2];
            c0 = fmaf(ws, hv.x, c0);
            c1 = fmaf(ws, hv.y, c1);
        }
        f16x2 o2 = { (f16)c0, (f16)c1 };
        *(f16x2*)(A16 + ((size_t)b * T + t) * 256 + H + lane * 2) = o2;
    }
}

// ---------- K5: out = combined(4096x256) @ fc_w(256xV) + fc_b   via fp16 MFMA.
// 512 blocks, 2/CU, whole grid co-resident. XCD-AWARE swizzle: all 32 blocks
// sharing an N-group land on ONE XCD (ni from bid&7) -> B working set per XCD
// = 2 MB < 4 MB L2, so B is fetched from HBM once (~16 MB) and re-reads hit L2.
// A-tile in registers; B chunks (64 cols, 32KB) double-buffered in LDS;
// counted vmcnt(4) keeps output stores off the critical path.
__global__ __launch_bounds__(512, 4) void k5_gemm(const f16* __restrict__ A16,
                                                  const f16* __restrict__ Bt16,
                                                  const float* __restrict__ fc_b,
                                                  float* __restrict__ out)
{
    __shared__ __align__(16) char Bs[2][32768];   // [buf][64 n][512 B k], XOR-swizzled
    int bid  = blockIdx.x;                 // 0..511
    int ni   = ((bid & 7) << 1) | (bid >> 8);   // 0..15, pinned to XCD = bid&7
    int mi   = (bid >> 3) & 31;            // 0..31
    int tid  = threadIdx.x;
    int w    = tid >> 6;                   // wave 0..7
    int lane = tid & 63;
    int l15  = lane & 15;
    int lhi  = lane >> 4;                  // 0..3

    // ---- A fragments: wave w owns rows mi*128 + w*16 .. +15 (32 VGPR/lane)
    const f16* Ab = A16 + (size_t)(mi * 128 + w * 16 + l15) * 256 + lhi * 8;
    f16x8 a[8];
    #pragma unroll
    for (int kt = 0; kt < 8; ++kt)
        a[kt] = *(const f16x8*)(Ab + kt * 32);

#define STAGE(cc, buf)                                                          \
    {                                                                           \
        const char* src = (const char*)(Bt16 + (size_t)(cc) * 64 * 256);        \
        _Pragma("unroll")                                                       \
        for (int it = 0; it < 4; ++it) {                                        \
            int ck  = it * 8 + w;                                               \
            int lin = ck * 1024 + lane * 16;                                    \
            int row = lin >> 9;                                                 \
            int g   = lin ^ ((row & 7) << 4);                                   \
            __builtin_amdgcn_global_load_lds(                                   \
                (const __attribute__((address_space(1))) void*)(src + g),       \
                (__attribute__((address_space(3))) void*)(&Bs[buf][0] + ck * 1024), \
                16, 0, 0);                                                      \
        }                                                                       \
    }

    STAGE(ni, 0);
    asm volatile("s_waitcnt vmcnt(0)");
    __syncthreads();

    int nc = (500 - ni + 15) >> 4;   // chunks c = ni + 16j < 500
    for (int j = 0; j < nc; ++j) {
        int c   = ni + j * 16;
        int cur = j & 1;

        if (j + 1 < nc) STAGE(c + 16, cur ^ 1);       // prefetch, issued first
        __builtin_amdgcn_sched_barrier(0);

        f32x4 acc[4];
        #pragma unroll
        for (int f = 0; f < 4; ++f)
            acc[f] = *(const f32x4*)(fc_b + c * 64 + f * 16 + lhi * 4);

        const char* bb = &Bs[cur][0];
        #pragma unroll
        for (int kt = 0; kt < 8; ++kt) {
            f16x8 bf[4];
            #pragma unroll
            for (int f = 0; f < 4; ++f) {
                int r  = f * 16 + l15;
                int ad = r * 512 + ((kt * 64 + lhi * 16) ^ ((r & 7) << 4));
                bf[f] = *(const f16x8*)(bb + ad);
            }
            #pragma unroll
            for (int f = 0; f < 4; ++f)
                acc[f] = __builtin_amdgcn_mfma_f32_16x16x32_f16(bf[f], a[kt], acc[f], 0, 0, 0);
        }

        int row = mi * 128 + w * 16 + l15;
        #pragma unroll
        for (int f = 0; f < 4; ++f)
            *(f32x4*)(out + (size_t)row * V + c * 64 + f * 16 + lhi * 4) = acc[f];

        if (j + 1 < nc) {
            __builtin_amdgcn_sched_barrier(0);
            asm volatile("s_waitcnt vmcnt(4)" ::: "memory");
            __builtin_amdgcn_s_barrier();
            __builtin_amdgcn_sched_barrier(0);
        }
    }
#undef STAGE
}

extern "C" void kernel_launch(void* const* d_in, const int* in_sizes, int n_in,
                              void* d_out, int out_size, void* d_ws, size_t ws_size,
                              hipStream_t stream)
{
    (void)in_sizes; (void)n_in; (void)out_size; (void)ws_size;
    const int*   x      = (const int*)  d_in[0];
    const float* emb    = (const float*)d_in[1];
    const float* W_ih   = (const float*)d_in[2];
    const float* W_hh   = (const float*)d_in[3];
    const float* bias   = (const float*)d_in[4];
    const float* attn_w = (const float*)d_in[5];
    const float* attn_b = (const float*)d_in[6];
    const float* v_w    = (const float*)d_in[7];
    const float* v_b    = (const float*)d_in[8];
    const float* fc_w   = (const float*)d_in[9];
    const float* fc_b   = (const float*)d_in[10];
    float* out = (float*)d_out;

    char* ws = (char*)d_ws;
    float* xg     = (float*)(ws);              // 4096*384*4 = 6,291,456 B
    f16*   A16    = (f16*)  (ws + 8404992);    // 4096*256*2 = 2,097,152 B
    f16*   Bt16   = (f16*)  (ws + 10502144);   // 32000*256*2 = 16,384,000 B

    hipLaunchKernelGGL(k0_convert_fcw, dim3(V / 256, 4), dim3(256), 0, stream, fc_w, Bt16);
    hipLaunchKernelGGL(k1_embed_xg,    dim3(B * T / 16), dim3(G3),  0, stream, x, emb, W_ih, bias, xg);
    hipLaunchKernelGGL(kseq,           dim3(B),          dim3(G3),  0, stream,
                       xg, W_hh, attn_w, attn_b, v_w, v_b, A16);
    hipLaunchKernelGGL(k5_gemm,        dim3(512),        dim3(512), 0, stream, A16, Bt16, fc_b, out);
}

// Round 9
// 502.691 us; speedup vs baseline: 2.4929x; 2.4929x over previous
//
#include <hip/hip_runtime.h>

typedef _Float16 f16;
typedef _Float16 f16x2 __attribute__((ext_vector_type(2)));
typedef _Float16 f16x8 __attribute__((ext_vector_type(8)));
typedef float    f32x4 __attribute__((ext_vector_type(4)));

#define V  32000
#define E  128
#define H  128
#define B  32
#define T  128
#define G3 384   // 3H

// ---------- K0: fc_w (256,V) f32  ->  Bt16 (V,256) f16 (transposed, converted)
__global__ __launch_bounds__(256) void k0_convert_fcw(const float* __restrict__ fc_w,
                                                      f16* __restrict__ Bt16)
{
    int v  = blockIdx.x * 256 + threadIdx.x;   // coalesced across lanes
    int k0 = blockIdx.y * 64;
    for (int kk = 0; kk < 64; kk += 8) {
        f16x8 p;
        #pragma unroll
        for (int e = 0; e < 8; ++e)
            p[e] = (f16)fc_w[(size_t)(k0 + kk + e) * V + v];
        *(f16x8*)(Bt16 + (size_t)v * 256 + (k0 + kk)) = p;
    }
}

// ---------- K1: xg = embedding[x] @ W_ih + b    (B*T, 3H)
__global__ __launch_bounds__(384) void k1_embed_xg(const int* __restrict__ x,
                                                   const float* __restrict__ emb,
                                                   const float* __restrict__ W_ih,
                                                   const float* __restrict__ bias,
                                                   float* __restrict__ xg)
{
    int j = threadIdx.x;
    float w[E];
    #pragma unroll
    for (int k = 0; k < E; ++k) w[k] = W_ih[k * G3 + j];
    float bj = bias[j];

    __shared__ __align__(16) float erow[16][E];
    int row0 = blockIdx.x * 16;
    for (int i = j; i < 16 * E; i += G3) {
        int r = i >> 7, c = i & (E - 1);
        erow[r][c] = emb[(size_t)x[row0 + r] * E + c];
    }
    __syncthreads();
    for (int r = 0; r < 16; ++r) {
        float acc = bj;
        #pragma unroll
        for (int k = 0; k < E; k += 4) {
            f32x4 hv = *(const f32x4*)&erow[r][k];
            acc += hv[0]*w[k] + hv[1]*w[k+1] + hv[2]*w[k+2] + hv[3]*w[k+3];
        }
        xg[(size_t)(row0 + r) * G3 + j] = acc;
    }
}

// ---------- KSEQ: fused GRU scan + scores + causal softmax/context.
// PHASE-SEPARATED so no two 128-float register arrays are ever live together
// (R8's interleaved version spilled: VGPR capped at 128 -> 1045us).
//  P1: scan, w[128] in regs (identical to known-good k2); hs -> LDS + A16.
//  P2: scores, NO register array: wave wv owns rows t=wv,wv+6,..; lane
//      accumulates cols lane & lane+64 reading attn_w from L1/L2.
//  P3: context from LDS (waves parallel over t).
__global__ __launch_bounds__(384, 1) void kseq(const float* __restrict__ xg,
                                               const float* __restrict__ W_hh,
                                               const float* __restrict__ attn_w,
                                               const float* __restrict__ attn_b,
                                               const float* __restrict__ v_w,
                                               const float* __restrict__ v_b,
                                               f16* __restrict__ A16)
{
    int b    = blockIdx.x;
    int j    = threadIdx.x;
    int lane = j & 63;
    int wv   = j >> 6;               // wave 0..5

    __shared__ __align__(16) float h[H];
    __shared__ float g[G3];
    __shared__ float sc_lds[T];
    __shared__ __align__(16) float hs_lds[T][H];   // 64KB
    if (j < H) h[j] = 0.0f;
    __syncthreads();

    // ---- Phase 1: GRU scan (only w[128] live)
    {
        float w[H];
        #pragma unroll
        for (int k = 0; k < H; ++k) w[k] = W_hh[k * G3 + j];

        const float* xgb = xg + (size_t)b * T * G3;
        float xnext = xgb[j];
        for (int t = 0; t < T; ++t) {
            float s0 = xnext, s1 = 0.f, s2 = 0.f, s3 = 0.f;
            if (t + 1 < T) xnext = xgb[(size_t)(t + 1) * G3 + j];
            #pragma unroll
            for (int k = 0; k < H; k += 16) {
                f32x4 h0 = *(const f32x4*)&h[k];
                f32x4 h1 = *(const f32x4*)&h[k + 4];
                f32x4 h2 = *(const f32x4*)&h[k + 8];
                f32x4 h3 = *(const f32x4*)&h[k + 12];
                s0 += h0[0]*w[k]    + h0[1]*w[k+1]  + h0[2]*w[k+2]  + h0[3]*w[k+3];
                s1 += h1[0]*w[k+4]  + h1[1]*w[k+5]  + h1[2]*w[k+6]  + h1[3]*w[k+7];
                s2 += h2[0]*w[k+8]  + h2[1]*w[k+9]  + h2[2]*w[k+10] + h2[3]*w[k+11];
                s3 += h3[0]*w[k+12] + h3[1]*w[k+13] + h3[2]*w[k+14] + h3[3]*w[k+15];
            }
            g[j] = (s0 + s1) + (s2 + s3);
            __syncthreads();
            if (j < H) {
                float z  = 1.0f / (1.0f + __expf(-g[j]));
                float r  = 1.0f / (1.0f + __expf(-g[H + j]));
                float pn = g[2 * H + j] * r;
                float ex = __expf(2.0f * pn);
                float n  = 1.0f - 2.0f / (ex + 1.0f);      // tanh(pn)
                float hn = (1.0f - z) * n + z * h[j];
                h[j] = hn;
                hs_lds[t][j] = hn;
                A16[((size_t)b * T + t) * 256 + j] = (f16)hn;
            }
            __syncthreads();
        }
    }

    // ---- Phase 2: scores. Wave wv owns t = wv, wv+6, ...; lane covers
    // columns lane and lane+64; attn_w read from cache (no reg array).
    {
        float ab0 = attn_b[lane], ab1 = attn_b[lane + 64];
        float vw0 = v_w[lane],    vw1 = v_w[lane + 64];
        float vb  = v_b[0];
        for (int t = wv; t < T; t += 6) {
            float a0 = ab0, a1 = ab1;
            for (int k = 0; k < H; k += 4) {
                f32x4 hv = *(const f32x4*)&hs_lds[t][k];
                a0 += hv[0]*attn_w[(k  )*H + lane] + hv[1]*attn_w[(k+1)*H + lane]
                    + hv[2]*attn_w[(k+2)*H + lane] + hv[3]*attn_w[(k+3)*H + lane];
                a1 += hv[0]*attn_w[(k  )*H + lane+64] + hv[1]*attn_w[(k+1)*H + lane+64]
                    + hv[2]*attn_w[(k+2)*H + lane+64] + hv[3]*attn_w[(k+3)*H + lane+64];
            }
            float e0 = __expf(2.0f * a0);
            float e1 = __expf(2.0f * a1);
            float u  = (1.0f - 2.0f / (e0 + 1.0f)) * vw0
                     + (1.0f - 2.0f / (e1 + 1.0f)) * vw1;
            #pragma unroll
            for (int o = 32; o > 0; o >>= 1) u += __shfl_xor(u, o);
            if (lane == 0) sc_lds[t] = u + vb;
        }
    }
    __syncthreads();

    // ---- Phase 3: context; wave per t, lane owns cols 2*lane, 2*lane+1
    for (int t = wv; t < T; t += 6) {
        float sv0 = (lane < t)      ? sc_lds[lane]      : -3.0e38f;
        float sv1 = (lane + 64 < t) ? sc_lds[lane + 64] : -3.0e38f;
        float m = fmaxf(sv0, sv1);
        #pragma unroll
        for (int o = 32; o > 0; o >>= 1) m = fmaxf(m, __shfl_xor(m, o));
        float ee = ((lane < t)      ? __expf(sv0 - m) : 0.f)
                 + ((lane + 64 < t) ? __expf(sv1 - m) : 0.f);
        #pragma unroll
        for (int o = 32; o > 0; o >>= 1) ee += __shfl_xor(ee, o);
        float inv = (t > 0) ? 1.0f / ee : 0.0f;

        float c0 = 0.f, c1 = 0.f;
        for (int s = 0; s < t; ++s) {
            float ws = __expf(sc_lds[s] - m) * inv;
            float2 hv = *(const float2*)&hs_lds[s][lane * 2];
            c0 = fmaf(ws, hv.x, c0);
            c1 = fmaf(ws, hv.y, c1);
        }
        f16x2 o2 = { (f16)c0, (f16)c1 };
        *(f16x2*)(A16 + ((size_t)b * T + t) * 256 + H + lane * 2) = o2;
    }
}

// ---------- K5: out = combined(4096x256) @ fc_w(256xV) + fc_b   via fp16 MFMA.
// 512 blocks, 2/CU, whole grid co-resident. XCD-AWARE swizzle: all 32 blocks
// sharing an N-group land on ONE XCD (ni from bid&7) -> B working set per XCD
// = 2 MB < 4 MB L2, so B is fetched from HBM once (~16 MB) and re-reads hit L2.
// A-tile in registers; B chunks (64 cols, 32KB) double-buffered in LDS;
// counted vmcnt(4) keeps output stores off the critical path.
__global__ __launch_bounds__(512, 4) void k5_gemm(const f16* __restrict__ A16,
                                                  const f16* __restrict__ Bt16,
                                                  const float* __restrict__ fc_b,
                                                  float* __restrict__ out)
{
    __shared__ __align__(16) char Bs[2][32768];   // [buf][64 n][512 B k], XOR-swizzled
    int bid  = blockIdx.x;                 // 0..511
    int ni   = ((bid & 7) << 1) | (bid >> 8);   // 0..15, pinned to XCD = bid&7
    int mi   = (bid >> 3) & 31;            // 0..31
    int tid  = threadIdx.x;
    int w    = tid >> 6;                   // wave 0..7
    int lane = tid & 63;
    int l15  = lane & 15;
    int lhi  = lane >> 4;                  // 0..3

    // ---- A fragments: wave w owns rows mi*128 + w*16 .. +15 (32 VGPR/lane)
    const f16* Ab = A16 + (size_t)(mi * 128 + w * 16 + l15) * 256 + lhi * 8;
    f16x8 a[8];
    #pragma unroll
    for (int kt = 0; kt < 8; ++kt)
        a[kt] = *(const f16x8*)(Ab + kt * 32);

#define STAGE(cc, buf)                                                          \
    {                                                                           \
        const char* src = (const char*)(Bt16 + (size_t)(cc) * 64 * 256);        \
        _Pragma("unroll")                                                       \
        for (int it = 0; it < 4; ++it) {                                        \
            int ck  = it * 8 + w;                                               \
            int lin = ck * 1024 + lane * 16;                                    \
            int row = lin >> 9;                                                 \
            int g   = lin ^ ((row & 7) << 4);                                   \
            __builtin_amdgcn_global_load_lds(                                   \
                (const __attribute__((address_space(1))) void*)(src + g),       \
                (__attribute__((address_space(3))) void*)(&Bs[buf][0] + ck * 1024), \
                16, 0, 0);                                                      \
        }                                                                       \
    }

    STAGE(ni, 0);
    asm volatile("s_waitcnt vmcnt(0)");
    __syncthreads();

    int nc = (500 - ni + 15) >> 4;   // chunks c = ni + 16j < 500
    for (int j = 0; j < nc; ++j) {
        int c   = ni + j * 16;
        int cur = j & 1;

        if (j + 1 < nc) STAGE(c + 16, cur ^ 1);       // prefetch, issued first
        __builtin_amdgcn_sched_barrier(0);

        f32x4 acc[4];
        #pragma unroll
        for (int f = 0; f < 4; ++f)
            acc[f] = *(const f32x4*)(fc_b + c * 64 + f * 16 + lhi * 4);

        const char* bb = &Bs[cur][0];
        #pragma unroll
        for (int kt = 0; kt < 8; ++kt) {
            f16x8 bf[4];
            #pragma unroll
            for (int f = 0; f < 4; ++f) {
                int r  = f * 16 + l15;
                int ad = r * 512 + ((kt * 64 + lhi * 16) ^ ((r & 7) << 4));
                bf[f] = *(const f16x8*)(bb + ad);
            }
            #pragma unroll
            for (int f = 0; f < 4; ++f)
                acc[f] = __builtin_amdgcn_mfma_f32_16x16x32_f16(bf[f], a[kt], acc[f], 0, 0, 0);
        }

        int row = mi * 128 + w * 16 + l15;
        #pragma unroll
        for (int f = 0; f < 4; ++f)
            *(f32x4*)(out + (size_t)row * V + c * 64 + f * 16 + lhi * 4) = acc[f];

        if (j + 1 < nc) {
            __builtin_amdgcn_sched_barrier(0);
            asm volatile("s_waitcnt vmcnt(4)" ::: "memory");
            __builtin_amdgcn_s_barrier();
            __builtin_amdgcn_sched_barrier(0);
        }
    }
#undef STAGE
}

extern "C" void kernel_launch(void* const* d_in, const int* in_sizes, int n_in,
                              void* d_out, int out_size, void* d_ws, size_t ws_size,
                              hipStream_t stream)
{
    (void)in_sizes; (void)n_in; (void)out_size; (void)ws_size;
    const int*   x      = (const int*)  d_in[0];
    const float* emb    = (const float*)d_in[1];
    const float* W_ih   = (const float*)d_in[2];
    const float* W_hh   = (const float*)d_in[3];
    const float* bias   = (const float*)d_in[4];
    const float* attn_w = (const float*)d_in[5];
    const float* attn_b = (const float*)d_in[6];
    const float* v_w    = (const float*)d_in[7];
    const float* v_b    = (const float*)d_in[8];
    const float* fc_w   = (const float*)d_in[9];
    const float* fc_b   = (const float*)d_in[10];
    float* out = (float*)d_out;

    char* ws = (char*)d_ws;
    float* xg     = (float*)(ws);              // 4096*384*4 = 6,291,456 B
    f16*   A16    = (f16*)  (ws + 8404992);    // 4096*256*2 = 2,097,152 B
    f16*   Bt16   = (f16*)  (ws + 10502144);   // 32000*256*2 = 16,384,000 B

    hipLaunchKernelGGL(k0_convert_fcw, dim3(V / 256, 4), dim3(256), 0, stream, fc_w, Bt16);
    hipLaunchKernelGGL(k1_embed_xg,    dim3(B * T / 16), dim3(G3),  0, stream, x, emb, W_ih, bias, xg);
    hipLaunchKernelGGL(kseq,           dim3(B),          dim3(G3),  0, stream,
                       xg, W_hh, attn_w, attn_b, v_w, v_b, A16);
    hipLaunchKernelGGL(k5_gemm,        dim3(512),        dim3(512), 0, stream, A16, Bt16, fc_b, out);
}

// Round 10
// 410.050 us; speedup vs baseline: 3.0561x; 1.2259x over previous
//
#include <hip/hip_runtime.h>

typedef _Float16 f16;
typedef _Float16 f16x2 __attribute__((ext_vector_type(2)));
typedef _Float16 f16x8 __attribute__((ext_vector_type(8)));
typedef float    f32x4 __attribute__((ext_vector_type(4)));

#define V  32000
#define E  128
#define H  128
#define B  32
#define T  128
#define G3 384   // 3H

// ---------- K0: fc_w (256,V) f32  ->  Bt16 (V,256) f16 (transposed, converted)
__global__ __launch_bounds__(256) void k0_convert_fcw(const float* __restrict__ fc_w,
                                                      f16* __restrict__ Bt16)
{
    int v  = blockIdx.x * 256 + threadIdx.x;   // coalesced across lanes
    int k0 = blockIdx.y * 64;
    for (int kk = 0; kk < 64; kk += 8) {
        f16x8 p;
        #pragma unroll
        for (int e = 0; e < 8; ++e)
            p[e] = (f16)fc_w[(size_t)(k0 + kk + e) * V + v];
        *(f16x8*)(Bt16 + (size_t)v * 256 + (k0 + kk)) = p;
    }
}

// ---------- K1: xg = embedding[x] @ W_ih + b    (B*T, 3H)
__global__ __launch_bounds__(384) void k1_embed_xg(const int* __restrict__ x,
                                                   const float* __restrict__ emb,
                                                   const float* __restrict__ W_ih,
                                                   const float* __restrict__ bias,
                                                   float* __restrict__ xg)
{
    int j = threadIdx.x;
    float w[E];
    #pragma unroll
    for (int k = 0; k < E; ++k) w[k] = W_ih[k * G3 + j];
    float bj = bias[j];

    __shared__ __align__(16) float erow[16][E];
    int row0 = blockIdx.x * 16;
    for (int i = j; i < 16 * E; i += G3) {
        int r = i >> 7, c = i & (E - 1);
        erow[r][c] = emb[(size_t)x[row0 + r] * E + c];
    }
    __syncthreads();
    for (int r = 0; r < 16; ++r) {
        float acc = bj;
        #pragma unroll
        for (int k = 0; k < E; k += 4) {
            f32x4 hv = *(const f32x4*)&erow[r][k];
            acc += hv[0]*w[k] + hv[1]*w[k+1] + hv[2]*w[k+2] + hv[3]*w[k+3];
        }
        xg[(size_t)(row0 + r) * G3 + j] = acc;
    }
}

// ---------- KSEQ v2: GRU scan + scores FUSED INTO THE SCAN DOT + context.
// 1024 threads = 2 k-halves x 512 columns (384 gate cols + 128 attn cols).
// Each thread holds only w[64] (~95 VGPR total -> no spill under any cap;
// R9's w[128] version was allocator-capped at 128 VGPR and spilled the scan).
// At step t the broadcast-dot on h_{t-1} produces gate partials AND the
// attention-score dot; waves 6-7 reduce the score while waves 0-1 do gates.
__global__ __launch_bounds__(1024) void kseq(const float* __restrict__ xg,
                                             const float* __restrict__ W_hh,
                                             const float* __restrict__ attn_w,
                                             const float* __restrict__ attn_b,
                                             const float* __restrict__ v_w,
                                             const float* __restrict__ v_b,
                                             f16* __restrict__ A16)
{
    int b    = blockIdx.x;
    int tid  = threadIdx.x;
    int half = tid >> 9;             // k-half 0/1
    int c    = tid & 511;            // column 0..511 (>=384 -> attn col c-384)
    int lane = tid & 63;
    int wv   = tid >> 6;             // wave 0..15

    __shared__ __align__(16) float h[H];
    __shared__ float part[2][512];
    __shared__ float sc_lds[T];
    __shared__ float pA[2];
    __shared__ __align__(16) float hs_lds[T][H];   // 64KB

    bool gatecol = (c < G3);
    float w[64];
    if (gatecol) {
        #pragma unroll
        for (int kk = 0; kk < 64; ++kk) w[kk] = W_hh[(half * 64 + kk) * G3 + c];
    } else {
        #pragma unroll
        for (int kk = 0; kk < 64; ++kk) w[kk] = attn_w[(half * 64 + kk) * H + (c - G3)];
    }
    float ab = 0.f, vwgt = 0.f;
    if (!gatecol) { ab = attn_b[c - G3]; vwgt = v_w[c - G3]; }
    float vb = v_b[0];

    if (tid < H) h[tid] = 0.0f;
    __syncthreads();

    const float* xgb = xg + (size_t)b * T * G3;
    float xnext = (half == 0 && gatecol) ? xgb[c] : 0.0f;

    for (int t = 0; t < T; ++t) {
        // partial dot over this thread's k-half of h_{t-1}
        float s0 = xnext, s1 = 0.f, s2 = 0.f, s3 = 0.f;
        if (half == 0 && gatecol && t + 1 < T) xnext = xgb[(size_t)(t + 1) * G3 + c];
        const float* hb = &h[half * 64];
        #pragma unroll
        for (int kk = 0; kk < 64; kk += 16) {
            f32x4 h0 = *(const f32x4*)&hb[kk];
            f32x4 h1 = *(const f32x4*)&hb[kk + 4];
            f32x4 h2 = *(const f32x4*)&hb[kk + 8];
            f32x4 h3 = *(const f32x4*)&hb[kk + 12];
            s0 += h0[0]*w[kk]    + h0[1]*w[kk+1]  + h0[2]*w[kk+2]  + h0[3]*w[kk+3];
            s1 += h1[0]*w[kk+4]  + h1[1]*w[kk+5]  + h1[2]*w[kk+6]  + h1[3]*w[kk+7];
            s2 += h2[0]*w[kk+8]  + h2[1]*w[kk+9]  + h2[2]*w[kk+10] + h2[3]*w[kk+11];
            s3 += h3[0]*w[kk+12] + h3[1]*w[kk+13] + h3[2]*w[kk+14] + h3[3]*w[kk+15];
        }
        part[half][c] = (s0 + s1) + (s2 + s3);
        __syncthreads();

        if (half == 0) {
            if (c < H) {               // waves 0-1: gate math + h update
                float iz  = part[0][c]       + part[1][c];
                float ir  = part[0][c + 128] + part[1][c + 128];
                float in_ = part[0][c + 256] + part[1][c + 256];
                float z  = 1.0f / (1.0f + __expf(-iz));
                float r  = 1.0f / (1.0f + __expf(-ir));
                float pn = in_ * r;
                float ex = __expf(2.0f * pn);
                float n  = 1.0f - 2.0f / (ex + 1.0f);      // tanh(pn)
                float hn = (1.0f - z) * n + z * h[c];
                h[c] = hn;
                hs_lds[t][c] = hn;
                A16[((size_t)b * T + t) * 256 + c] = (f16)hn;
            } else if (c >= G3) {      // waves 6-7: score reduce for h_{t-1}
                float sf = part[0][c] + part[1][c] + ab;
                float ex = __expf(2.0f * sf);
                float u  = (1.0f - 2.0f / (ex + 1.0f)) * vwgt;
                #pragma unroll
                for (int o = 32; o > 0; o >>= 1) u += __shfl_xor(u, o);
                if (lane == 0) pA[wv - 6] = u;
            }
        }
        __syncthreads();
        if (tid == 0 && t > 0) sc_lds[t - 1] = pA[0] + pA[1] + vb;
    }
    __syncthreads();   // sc_lds[126] visible to all

    // ---- context phase: 16 waves x exactly 8 t-rows; lane owns cols 2l,2l+1
    for (int t = wv; t < T; t += 16) {
        float sv0 = (lane < t)      ? sc_lds[lane]      : -3.0e38f;
        float sv1 = (lane + 64 < t) ? sc_lds[lane + 64] : -3.0e38f;
        float m = fmaxf(sv0, sv1);
        #pragma unroll
        for (int o = 32; o > 0; o >>= 1) m = fmaxf(m, __shfl_xor(m, o));
        float ee = ((lane < t)      ? __expf(sv0 - m) : 0.f)
                 + ((lane + 64 < t) ? __expf(sv1 - m) : 0.f);
        #pragma unroll
        for (int o = 32; o > 0; o >>= 1) ee += __shfl_xor(ee, o);
        float inv = (t > 0) ? 1.0f / ee : 0.0f;

        float c0 = 0.f, c1 = 0.f;
        for (int s = 0; s < t; ++s) {
            float ws = __expf(sc_lds[s] - m) * inv;
            float2 hv = *(const float2*)&hs_lds[s][lane * 2];
            c0 = fmaf(ws, hv.x, c0);
            c1 = fmaf(ws, hv.y, c1);
        }
        f16x2 o2 = { (f16)c0, (f16)c1 };
        *(f16x2*)(A16 + ((size_t)b * T + t) * 256 + H + lane * 2) = o2;
    }
}

// ---------- K5: out = combined(4096x256) @ fc_w(256xV) + fc_b   via fp16 MFMA.
// 512 blocks, 2/CU, whole grid co-resident. XCD-pinned ni (bid&7); A-tile in
// registers; B chunks (64 cols, 32KB) double-buffered; counted vmcnt(4).
__global__ __launch_bounds__(512, 4) void k5_gemm(const f16* __restrict__ A16,
                                                  const f16* __restrict__ Bt16,
                                                  const float* __restrict__ fc_b,
                                                  float* __restrict__ out)
{
    __shared__ __align__(16) char Bs[2][32768];   // [buf][64 n][512 B k], XOR-swizzled
    int bid  = blockIdx.x;                 // 0..511
    int ni   = ((bid & 7) << 1) | (bid >> 8);   // 0..15, pinned to XCD = bid&7
    int mi   = (bid >> 3) & 31;            // 0..31
    int tid  = threadIdx.x;
    int w    = tid >> 6;                   // wave 0..7
    int lane = tid & 63;
    int l15  = lane & 15;
    int lhi  = lane >> 4;                  // 0..3

    const f16* Ab = A16 + (size_t)(mi * 128 + w * 16 + l15) * 256 + lhi * 8;
    f16x8 a[8];
    #pragma unroll
    for (int kt = 0; kt < 8; ++kt)
        a[kt] = *(const f16x8*)(Ab + kt * 32);

#define STAGE(cc, buf)                                                          \
    {                                                                           \
        const char* src = (const char*)(Bt16 + (size_t)(cc) * 64 * 256);        \
        _Pragma("unroll")                                                       \
        for (int it = 0; it < 4; ++it) {                                        \
            int ck  = it * 8 + w;                                               \
            int lin = ck * 1024 + lane * 16;                                    \
            int row = lin >> 9;                                                 \
            int g   = lin ^ ((row & 7) << 4);                                   \
            __builtin_amdgcn_global_load_lds(                                   \
                (const __attribute__((address_space(1))) void*)(src + g),       \
                (__attribute__((address_space(3))) void*)(&Bs[buf][0] + ck * 1024), \
                16, 0, 0);                                                      \
        }                                                                       \
    }

    STAGE(ni, 0);
    asm volatile("s_waitcnt vmcnt(0)");
    __syncthreads();

    int nc = (500 - ni + 15) >> 4;   // chunks c = ni + 16j < 500
    for (int j = 0; j < nc; ++j) {
        int c   = ni + j * 16;
        int cur = j & 1;

        if (j + 1 < nc) STAGE(c + 16, cur ^ 1);       // prefetch, issued first
        __builtin_amdgcn_sched_barrier(0);

        f32x4 acc[4];
        #pragma unroll
        for (int f = 0; f < 4; ++f)
            acc[f] = *(const f32x4*)(fc_b + c * 64 + f * 16 + lhi * 4);

        const char* bb = &Bs[cur][0];
        #pragma unroll
        for (int kt = 0; kt < 8; ++kt) {
            f16x8 bf[4];
            #pragma unroll
            for (int f = 0; f < 4; ++f) {
                int r  = f * 16 + l15;
                int ad = r * 512 + ((kt * 64 + lhi * 16) ^ ((r & 7) << 4));
                bf[f] = *(const f16x8*)(bb + ad);
            }
            #pragma unroll
            for (int f = 0; f < 4; ++f)
                acc[f] = __builtin_amdgcn_mfma_f32_16x16x32_f16(bf[f], a[kt], acc[f], 0, 0, 0);
        }

        int row = mi * 128 + w * 16 + l15;
        #pragma unroll
        for (int f = 0; f < 4; ++f)
            *(f32x4*)(out + (size_t)row * V + c * 64 + f * 16 + lhi * 4) = acc[f];

        if (j + 1 < nc) {
            __builtin_amdgcn_sched_barrier(0);
            asm volatile("s_waitcnt vmcnt(4)" ::: "memory");
            __builtin_amdgcn_s_barrier();
            __builtin_amdgcn_sched_barrier(0);
        }
    }
#undef STAGE
}

extern "C" void kernel_launch(void* const* d_in, const int* in_sizes, int n_in,
                              void* d_out, int out_size, void* d_ws, size_t ws_size,
                              hipStream_t stream)
{
    (void)in_sizes; (void)n_in; (void)out_size; (void)ws_size;
    const int*   x      = (const int*)  d_in[0];
    const float* emb    = (const float*)d_in[1];
    const float* W_ih   = (const float*)d_in[2];
    const float* W_hh   = (const float*)d_in[3];
    const float* bias   = (const float*)d_in[4];
    const float* attn_w = (const float*)d_in[5];
    const float* attn_b = (const float*)d_in[6];
    const float* v_w    = (const float*)d_in[7];
    const float* v_b    = (const float*)d_in[8];
    const float* fc_w   = (const float*)d_in[9];
    const float* fc_b   = (const float*)d_in[10];
    float* out = (float*)d_out;

    char* ws = (char*)d_ws;
    float* xg     = (float*)(ws);              // 4096*384*4 = 6,291,456 B
    f16*   A16    = (f16*)  (ws + 8404992);    // 4096*256*2 = 2,097,152 B
    f16*   Bt16   = (f16*)  (ws + 10502144);   // 32000*256*2 = 16,384,000 B

    hipLaunchKernelGGL(k0_convert_fcw, dim3(V / 256, 4), dim3(256),  0, stream, fc_w, Bt16);
    hipLaunchKernelGGL(k1_embed_xg,    dim3(B * T / 16), dim3(G3),   0, stream, x, emb, W_ih, bias, xg);
    hipLaunchKernelGGL(kseq,           dim3(B),          dim3(1024), 0, stream,
                       xg, W_hh, attn_w, attn_b, v_w, v_b, A16);
    hipLaunchKernelGGL(k5_gemm,        dim3(512),        dim3(512),  0, stream, A16, Bt16, fc_b, out);
}